// Round 1
// baseline (198.364 us; speedup 1.0000x reference)
//
#include <hip/hip_runtime.h>
#include <hip/hip_bf16.h>
#include <stdint.h>

typedef __bf16 bf16;
typedef __bf16 bf16x8 __attribute__((ext_vector_type(8)));
typedef __bf16 bf16x4 __attribute__((ext_vector_type(4)));
typedef float  f32x4  __attribute__((ext_vector_type(4)));

#define MFMA16(A, B, C) __builtin_amdgcn_mfma_f32_16x16x32_bf16((A), (B), (C), 0, 0, 0)

static constexpr int Bsz = 4, Seq = 2048, Dm = 512, Hh = 8, Dh = 64;
static constexpr float ATT_SCALE = 0.125f;  // 64^-0.5

__device__ __forceinline__ void g2l_16(void* lds, const void* gp) {
  __builtin_amdgcn_global_load_lds((__attribute__((address_space(1))) void*)gp,
                                   (__attribute__((address_space(3))) void*)lds, 16, 0, 0);
}

// ---------------- LayerNorm fp32 -> bf16, one wave per row (D=512) ----------------
__global__ __launch_bounds__(256) void ln_cast_kernel(
    const float* __restrict__ x, const float* __restrict__ g,
    const float* __restrict__ be, bf16* __restrict__ xn) {
  const int row  = blockIdx.x * 4 + (threadIdx.x >> 6);
  const int lane = threadIdx.x & 63;
  const f32x4* xr = (const f32x4*)(x + (size_t)row * Dm);
  f32x4 v0 = xr[lane];
  f32x4 v1 = xr[lane + 64];
  float s = (v0.x + v0.y + v0.z + v0.w) + (v1.x + v1.y + v1.z + v1.w);
#pragma unroll
  for (int off = 32; off > 0; off >>= 1) s += __shfl_xor(s, off);
  const float mu = s * (1.0f / Dm);
  f32x4 d0 = v0 - mu, d1 = v1 - mu;
  float q = d0.x * d0.x + d0.y * d0.y + d0.z * d0.z + d0.w * d0.w
          + d1.x * d1.x + d1.y * d1.y + d1.z * d1.z + d1.w * d1.w;
#pragma unroll
  for (int off = 32; off > 0; off >>= 1) q += __shfl_xor(q, off);
  const float rs = rsqrtf(q * (1.0f / Dm) + 1e-5f);
  const f32x4* gr = (const f32x4*)g;
  const f32x4* br = (const f32x4*)be;
  f32x4 g0 = gr[lane], g1 = gr[lane + 64];
  f32x4 b0 = br[lane], b1 = br[lane + 64];
  f32x4 y0 = d0 * rs * g0 + b0;
  f32x4 y1 = d1 * rs * g1 + b1;
  bf16x4 o0 = { (bf16)y0.x, (bf16)y0.y, (bf16)y0.z, (bf16)y0.w };
  bf16x4 o1 = { (bf16)y1.x, (bf16)y1.y, (bf16)y1.z, (bf16)y1.w };
  bf16x4* orow = (bf16x4*)(xn + (size_t)row * Dm);
  orow[lane]      = o0;
  orow[lane + 64] = o1;
}

// ---------------- transpose + cast: src[R][C] f32 -> dst[C][R] bf16 ----------------
__global__ __launch_bounds__(256) void tcast_kernel(
    const float* __restrict__ src, bf16* __restrict__ dst, int R, int C) {
  __shared__ float t[32][33];
  const int c0 = blockIdx.x * 32, r0 = blockIdx.y * 32;
  const int tx = threadIdx.x & 31, ty = threadIdx.x >> 5;
#pragma unroll
  for (int i = 0; i < 32; i += 8)
    t[ty + i][tx] = src[(size_t)(r0 + ty + i) * C + c0 + tx];
  __syncthreads();
#pragma unroll
  for (int i = 0; i < 32; i += 8)
    dst[(size_t)(c0 + ty + i) * R + r0 + tx] = (bf16)t[tx][ty + i];
}

// ---------------- QKV GEMM: [8192,512] x [512,1536] -> Q/K/V [B,H,S,64] bf16 -------
// 128x128x32 tile, 4 waves (2x2 of 64x64), m97-style global_load_lds staging.
__global__ __launch_bounds__(256) void gemm_qkv_kernel(
    const bf16* __restrict__ A,   // [8192][512]
    const bf16* __restrict__ Bt,  // [1536][512]  (w_qkv transposed)
    bf16* __restrict__ Qb, bf16* __restrict__ Kb, bf16* __restrict__ Vb) {
  constexpr int K = 512;
  __shared__ __align__(16) bf16 As[128 * 32];
  __shared__ __align__(16) bf16 Bs[128 * 32];
  const int m0 = blockIdx.x * 128, n0 = blockIdx.y * 128;
  const int tid = threadIdx.x, lane = tid & 63, wave = tid >> 6;
  const int lr = lane & 15, lg = lane >> 4;
  const int wm = (wave >> 1) * 64, wn = (wave & 1) * 64;
  const int srow = wave * 16 + (lane >> 2);
  const int scol = (lane & 3) * 8;
  const bf16* ga = A  + (size_t)(m0 + srow) * K + scol;
  const bf16* gb = Bt + (size_t)(n0 + srow) * K + scol;
  bf16* lA = As + wave * 512;  // 1024B per wave, lane writes +lane*16B
  bf16* lB = Bs + wave * 512;
  f32x4 acc[4][4] = {};
  for (int k0 = 0; k0 < K; k0 += 32) {
    g2l_16(lA,        ga + k0);
    g2l_16(lA + 2048, ga + (size_t)64 * K + k0);
    g2l_16(lB,        gb + k0);
    g2l_16(lB + 2048, gb + (size_t)64 * K + k0);
    asm volatile("s_waitcnt vmcnt(0)" ::: "memory");
    __syncthreads();
    bf16x8 af[4], bfr[4];
#pragma unroll
    for (int i = 0; i < 4; ++i)
      af[i] = *(const bf16x8*)&As[(wm + i * 16 + lr) * 32 + lg * 8];
#pragma unroll
    for (int j = 0; j < 4; ++j)
      bfr[j] = *(const bf16x8*)&Bs[(wn + j * 16 + lr) * 32 + lg * 8];
#pragma unroll
    for (int i = 0; i < 4; ++i)
#pragma unroll
      for (int j = 0; j < 4; ++j)
        acc[i][j] = MFMA16(af[i], bfr[j], acc[i][j]);
    __syncthreads();
  }
#pragma unroll
  for (int j = 0; j < 4; ++j) {
    const int n = n0 + wn + j * 16 + lr;
    const int which = n >> 9, h = (n >> 6) & 7, dh = n & 63;
    bf16* dst = which == 0 ? Qb : (which == 1 ? Kb : Vb);
#pragma unroll
    for (int i = 0; i < 4; ++i) {
#pragma unroll
      for (int r = 0; r < 4; ++r) {
        const int m = m0 + wm + i * 16 + lg * 4 + r;
        const int b = m >> 11, s2 = m & 2047;
        dst[((size_t)((b * Hh + h) * Seq + s2) << 6) | dh] = (bf16)acc[i][j][r];
      }
    }
  }
}

// ---------------- Out GEMM: [8192,512] x [512,512] + bias -> fp32 out --------------
__global__ __launch_bounds__(256) void gemm_out_kernel(
    const bf16* __restrict__ A,   // [8192][512] attention output
    const bf16* __restrict__ Bt,  // [512][512]  (w_out transposed)
    const float* __restrict__ bias, float* __restrict__ out) {
  constexpr int K = 512;
  __shared__ __align__(16) bf16 As[128 * 32];
  __shared__ __align__(16) bf16 Bs[128 * 32];
  const int m0 = blockIdx.x * 128, n0 = blockIdx.y * 128;
  const int tid = threadIdx.x, lane = tid & 63, wave = tid >> 6;
  const int lr = lane & 15, lg = lane >> 4;
  const int wm = (wave >> 1) * 64, wn = (wave & 1) * 64;
  const int srow = wave * 16 + (lane >> 2);
  const int scol = (lane & 3) * 8;
  const bf16* ga = A  + (size_t)(m0 + srow) * K + scol;
  const bf16* gb = Bt + (size_t)(n0 + srow) * K + scol;
  bf16* lA = As + wave * 512;
  bf16* lB = Bs + wave * 512;
  f32x4 acc[4][4] = {};
  for (int k0 = 0; k0 < K; k0 += 32) {
    g2l_16(lA,        ga + k0);
    g2l_16(lA + 2048, ga + (size_t)64 * K + k0);
    g2l_16(lB,        gb + k0);
    g2l_16(lB + 2048, gb + (size_t)64 * K + k0);
    asm volatile("s_waitcnt vmcnt(0)" ::: "memory");
    __syncthreads();
    bf16x8 af[4], bfr[4];
#pragma unroll
    for (int i = 0; i < 4; ++i)
      af[i] = *(const bf16x8*)&As[(wm + i * 16 + lr) * 32 + lg * 8];
#pragma unroll
    for (int j = 0; j < 4; ++j)
      bfr[j] = *(const bf16x8*)&Bs[(wn + j * 16 + lr) * 32 + lg * 8];
#pragma unroll
    for (int i = 0; i < 4; ++i)
#pragma unroll
      for (int j = 0; j < 4; ++j)
        acc[i][j] = MFMA16(af[i], bfr[j], acc[i][j]);
    __syncthreads();
  }
#pragma unroll
  for (int j = 0; j < 4; ++j) {
    const int n = n0 + wn + j * 16 + lr;
    const float bv = bias[n];
#pragma unroll
    for (int i = 0; i < 4; ++i)
#pragma unroll
      for (int r = 0; r < 4; ++r) {
        const int m = m0 + wm + i * 16 + lg * 4 + r;
        out[(size_t)m * 512 + n] = acc[i][j][r] + bv;
      }
  }
}

// ---------------- Flash attention: QBLK=128 (4 waves x 32 rows), KVBLK=64 ----------
__global__ __launch_bounds__(256) void attn_kernel(
    const bf16* __restrict__ Qb, const bf16* __restrict__ Kb,
    const bf16* __restrict__ Vb, bf16* __restrict__ A2) {
  const int bh = blockIdx.y;          // b*8+h
  const int b  = bh >> 3, h = bh & 7;
  const int q0 = blockIdx.x * 128;
  const int tid = threadIdx.x, lane = tid & 63, wave = tid >> 6;
  const int lr = lane & 15, lg = lane >> 4;
  const bf16* Qh = Qb + (size_t)bh * Seq * Dh;
  const bf16* Kh = Kb + (size_t)bh * Seq * Dh;
  const bf16* Vh = Vb + (size_t)bh * Seq * Dh;
  __shared__ __align__(16) bf16 Vt[64][72];          // [feat][key(+pad)]
  __shared__ __align__(16) bf16 Pl[4][2][16 * 64];   // wave-private P tiles

  bf16x8 qf[2][2];
#pragma unroll
  for (int r = 0; r < 2; ++r)
#pragma unroll
    for (int ks = 0; ks < 2; ++ks)
      qf[r][ks] = *(const bf16x8*)&Qh[(size_t)(q0 + wave * 32 + r * 16 + lr) * 64 + ks * 32 + lg * 8];

  f32x4 o[2][4] = {};
  float mrow[2][4], lsum[2][4];
#pragma unroll
  for (int r = 0; r < 2; ++r)
#pragma unroll
    for (int j = 0; j < 4; ++j) { mrow[r][j] = -1e30f; lsum[r][j] = 0.0f; }

  const int vkey = tid & 63, vf0 = (tid >> 6) * 8;

  for (int t0 = 0; t0 < Seq; t0 += 64) {
    // stage V tile transposed into LDS
    {
      bf16x8 va = *(const bf16x8*)&Vh[(size_t)(t0 + vkey) * 64 + vf0];
      bf16x8 vc = *(const bf16x8*)&Vh[(size_t)(t0 + vkey) * 64 + vf0 + 32];
#pragma unroll
      for (int jj = 0; jj < 8; ++jj) {
        Vt[vf0 + jj][vkey]      = va[jj];
        Vt[vf0 + 32 + jj][vkey] = vc[jj];
      }
    }
    // S = Q K^T  (per wave: 32 q-rows x 64 keys)
    f32x4 sacc[2][4] = {};
#pragma unroll
    for (int c = 0; c < 4; ++c) {
      const bf16* kb = &Kh[(size_t)(t0 + c * 16 + lr) * 64 + lg * 8];
      bf16x8 kf0 = *(const bf16x8*)kb;
      bf16x8 kf1 = *(const bf16x8*)(kb + 32);
      sacc[0][c] = MFMA16(qf[0][0], kf0, sacc[0][c]);
      sacc[0][c] = MFMA16(qf[0][1], kf1, sacc[0][c]);
      sacc[1][c] = MFMA16(qf[1][0], kf0, sacc[1][c]);
      sacc[1][c] = MFMA16(qf[1][1], kf1, sacc[1][c]);
    }
    // online softmax
#pragma unroll
    for (int r = 0; r < 2; ++r) {
      float al[4];
#pragma unroll
      for (int j = 0; j < 4; ++j) {
        float s0 = sacc[r][0][j] * ATT_SCALE;
        float s1 = sacc[r][1][j] * ATT_SCALE;
        float s2 = sacc[r][2][j] * ATT_SCALE;
        float s3 = sacc[r][3][j] * ATT_SCALE;
        float mx = fmaxf(fmaxf(s0, s1), fmaxf(s2, s3));
#pragma unroll
        for (int off = 1; off < 16; off <<= 1) mx = fmaxf(mx, __shfl_xor(mx, off));
        const float mo = mrow[r][j];
        const float mn = fmaxf(mo, mx);
        const float a  = __expf(mo - mn);
        const float p0 = __expf(s0 - mn), p1 = __expf(s1 - mn);
        const float p2 = __expf(s2 - mn), p3 = __expf(s3 - mn);
        float ps = (p0 + p1) + (p2 + p3);
#pragma unroll
        for (int off = 1; off < 16; off <<= 1) ps += __shfl_xor(ps, off);
        lsum[r][j] = lsum[r][j] * a + ps;
        mrow[r][j] = mn;
        al[j] = a;
        bf16* prow = &Pl[wave][r][(lg * 4 + j) * 64 + lr];
        prow[0]  = (bf16)p0;
        prow[16] = (bf16)p1;
        prow[32] = (bf16)p2;
        prow[48] = (bf16)p3;
      }
#pragma unroll
      for (int n = 0; n < 4; ++n) {
        o[r][n].x *= al[0]; o[r][n].y *= al[1]; o[r][n].z *= al[2]; o[r][n].w *= al[3];
      }
    }
    __syncthreads();   // Vt staged by all waves, P visible
    // O += P V
#pragma unroll
    for (int r = 0; r < 2; ++r) {
      bf16x8 pf0 = *(const bf16x8*)&Pl[wave][r][lr * 64 + lg * 8];
      bf16x8 pf1 = *(const bf16x8*)&Pl[wave][r][lr * 64 + 32 + lg * 8];
#pragma unroll
      for (int n = 0; n < 4; ++n) {
        bf16x8 vf0 = *(const bf16x8*)&Vt[n * 16 + lr][lg * 8];
        bf16x8 vf1 = *(const bf16x8*)&Vt[n * 16 + lr][32 + lg * 8];
        o[r][n] = MFMA16(pf0, vf0, o[r][n]);
        o[r][n] = MFMA16(pf1, vf1, o[r][n]);
      }
    }
    __syncthreads();   // protect Vt before next stage
  }
  // epilogue: normalize and write [B*S, 512] bf16
#pragma unroll
  for (int r = 0; r < 2; ++r) {
    float inv[4];
#pragma unroll
    for (int j = 0; j < 4; ++j) inv[j] = 1.0f / lsum[r][j];
#pragma unroll
    for (int n = 0; n < 4; ++n)
#pragma unroll
      for (int j = 0; j < 4; ++j) {
        const int s2 = q0 + wave * 32 + r * 16 + lg * 4 + j;
        A2[(size_t)(b * Seq + s2) * 512 + h * 64 + n * 16 + lr] = (bf16)(o[r][n][j] * inv[j]);
      }
  }
}

extern "C" void kernel_launch(void* const* d_in, const int* in_sizes, int n_in,
                              void* d_out, int out_size, void* d_ws, size_t ws_size,
                              hipStream_t stream) {
  const float* x    = (const float*)d_in[0];
  const float* gam  = (const float*)d_in[1];
  const float* bet  = (const float*)d_in[2];
  const float* wqkv = (const float*)d_in[3];  // [512][1536]
  const float* wout = (const float*)d_in[4];  // [512][512]
  const float* bout = (const float*)d_in[5];  // [512]
  float* out = (float*)d_out;

  bf16* xn    = (bf16*)d_ws;                        // [8192][512]   8 MB
  bf16* wqkvT = xn    + (size_t)8192 * 512;         // [1536][512]   1.5 MB
  bf16* woutT = wqkvT + (size_t)1536 * 512;         // [512][512]    0.5 MB
  bf16* Qb    = woutT + (size_t)512 * 512;          // [4,8,2048,64] 8 MB
  bf16* Kb    = Qb    + (size_t)4 * 8 * 2048 * 64;
  bf16* Vb    = Kb    + (size_t)4 * 8 * 2048 * 64;
  bf16* A2    = xn;  // reuse: xn dead after QKV GEMM

  ln_cast_kernel<<<2048, 256, 0, stream>>>(x, gam, bet, xn);
  tcast_kernel<<<dim3(48, 16), 256, 0, stream>>>(wqkv, wqkvT, 512, 1536);
  tcast_kernel<<<dim3(16, 16), 256, 0, stream>>>(wout, woutT, 512, 512);
  gemm_qkv_kernel<<<dim3(64, 12), 256, 0, stream>>>(xn, wqkvT, Qb, Kb, Vb);
  attn_kernel<<<dim3(16, 32), 256, 0, stream>>>(Qb, Kb, Vb, A2);
  gemm_out_kernel<<<dim3(64, 4), 256, 0, stream>>>(A2, woutT, bout, out);
}